// Round 8
// baseline (332.154 us; speedup 1.0000x reference)
//
#include <hip/hip_runtime.h>

typedef unsigned short u16;
typedef unsigned int   u32;
typedef __bf16 bf16;
typedef bf16  bf16x8 __attribute__((ext_vector_type(8)));
typedef float f32x16 __attribute__((ext_vector_type(16)));

__device__ __forceinline__ u16 bf16u(float f) {
    u32 x = __builtin_bit_cast(u32, f);
    x += 0x7fffu + ((x >> 16) & 1u);   // RNE
    return (u16)(x >> 16);
}

__device__ __forceinline__ void gl_lds16(const void* g, void* l) {
    __builtin_amdgcn_global_load_lds(
        (const __attribute__((address_space(1))) u32*)g,
        (__attribute__((address_space(3))) u32*)l, 16, 0, 0);
}

// ---------------- fp32 -> bf16 convert (vectorized) ----------------
__global__ __launch_bounds__(256) void cvt_x_kernel(const float4* __restrict__ in,
                                                    ushort4* __restrict__ out, int n4) {
    int i = blockIdx.x * 256 + threadIdx.x;
    if (i >= n4) return;
    float4 f = in[i];
    ushort4 o;
    o.x = bf16u(f.x); o.y = bf16u(f.y); o.z = bf16u(f.z); o.w = bf16u(f.w);
    out[i] = o;
}

// ------- all 4 weight transposes in one kernel (fp32 W -> bf16 W^T) --------
__global__ __launch_bounds__(256) void transp_all(
    const float* __restrict__ Wq, const float* __restrict__ Wk,
    const float* __restrict__ Wv, const float* __restrict__ Wo,
    u16* __restrict__ WqkvT, u16* __restrict__ WoT)
{
    const int z = blockIdx.z;
    const float* W; u16* WT; int rows, cols;
    if (z < 3) {
        if (blockIdx.y >= 32) return;
        W = (z == 0) ? Wq : (z == 1) ? Wk : Wv;
        WT = WqkvT + (size_t)z * 1024 * 1024;
        rows = 1024; cols = 1024;
    } else {
        W = Wo; WT = WoT; rows = 2048; cols = 1024;
    }
    __shared__ float t[32][33];
    int bx = blockIdx.x * 32, by = blockIdx.y * 32;
    int x = threadIdx.x & 31, y = threadIdx.x >> 5;
#pragma unroll
    for (int i = 0; i < 32; i += 8)
        t[y + i][x] = W[(size_t)(by + y + i) * cols + bx + x];
    __syncthreads();
#pragma unroll
    for (int i = 0; i < 32; i += 8)
        WT[(size_t)(bx + y + i) * rows + by + x] = bf16u(t[x][y + i]);
}

// ==== 256x256 GEMM, BK=32, 3-buffer, fat phase, 32x32x16 MFMA ====
// C[M][N] = A[M][K]*BT[N][K]^T. 512 thr = 8 waves (2M x 4N), wave 128x64
// as 4x2 tiles of 32x32. LDS: 3 bufs x (A[256][32]+B[256][32]) x 2B = 96 KB.
// Phase t: {12 ds_read | stage t+2} BAR; 16 MFMA 32x32x16 (setprio);
// publish t+1 via counted vmcnt(4); BAR; SB0. Single stage point per phase
// -> vmcnt order == tile order.
// A/B frag (32x32x16): row = lane&31, k = (lane>>5)*8 + j  (8 bf16 contiguous).
// Chunk swizzle: phys16B = (2s + (lane>>5)) ^ ((lane>>1)&3)  -> lanes 0..7
// cover a full 128B bank sweep: conflict-free. Same physical layout as the
// staging inverse-swizzle (unchanged from r7).
// C/D: col = lane&31, row = (reg&3) + 8*(reg>>2) + 4*(lane>>5)  [m74/m101].
#define BAR   __builtin_amdgcn_s_barrier()
#define SB0   __builtin_amdgcn_sched_barrier(0)
#define VM4   asm volatile("s_waitcnt vmcnt(4)" ::: "memory")
#define VM0   asm volatile("s_waitcnt vmcnt(0)" ::: "memory")

__global__ __launch_bounds__(512, 2) void gemm8(
    const u16* __restrict__ A, const u16* __restrict__ BT, void* __restrict__ Cout,
    const float* __restrict__ cosp, const float* __restrict__ sinp,
    int M, int N, int K, int mode)
{
    __shared__ u16 Ld[3][16384];   // per buf: A @0 (8192 u16), B @8192
    const int tid = threadIdx.x;
    const int wid = tid >> 6, lane = tid & 63;
    const int nx = gridDim.x;
    const int nwg = nx * gridDim.y;
    const int orig = blockIdx.y * nx + blockIdx.x;
    const int vid = (orig & 7) * (nwg >> 3) + (orig >> 3);
    const int m0 = (vid / nx) << 8, n0 = (vid % nx) << 8;
    const int wr = wid >> 2, wc = wid & 3;

    // ---- staging descriptors: 4 gl_lds per thread per K-tile (r7, unchanged) ----
    const int srow = tid >> 2;                     // row 0..127
    const int sl = (tid & 3) ^ ((srow >> 1) & 3);  // inverse-swizzled chunk
    const u16* aS0 = A + (size_t)(m0 + srow) * K + (sl << 3);
    const u16* aS1 = aS0 + (size_t)128 * K;
    const u16* bS0 = BT + (size_t)(n0 + srow) * K + (sl << 3);
    const u16* bS1 = bS0 + (size_t)128 * K;
    const int wdb = wid << 9;                      // wave-uniform dest (u16)
    const int nt = K >> 5;

#define STAGE(T, B_) do { if ((T) < nt) { size_t _ko = (size_t)(T) << 5; \
        gl_lds16(aS0 + _ko, &Ld[B_][wdb]); \
        gl_lds16(aS1 + _ko, &Ld[B_][4096 + wdb]); \
        gl_lds16(bS0 + _ko, &Ld[B_][8192 + wdb]); \
        gl_lds16(bS1 + _ko, &Ld[B_][12288 + wdb]); } } while (0)

    // frag reads: swizzled 16B-chunk offsets for k-slice 0/1 (u16 units)
    const int ph0 = (((lane >> 5))     ^ ((lane >> 1) & 3)) << 3;  // s=0: c=lane>>5
    const int ph1 = (((lane >> 5) + 2) ^ ((lane >> 1) & 3)) << 3;  // s=1: c=2+(lane>>5)
    const int raw = ((wr << 7) + (lane & 31)) << 5;            // A row base (u16)
    const int rbw = (((wc << 6) + (lane & 31)) << 5) + 8192;   // B row base (u16)

    f32x16 acc[4][2] = {};

    STAGE(0, 0); STAGE(1, 1);
    VM4;                       // tile 0 landed; tile 1 (4 loads) in flight
    BAR; SB0;

    int b = 0, bs = 2;
    for (int t = 0; t < nt; ++t) {
        const u16* Lb = &Ld[b][0];
        bf16x8 fa[4][2], fb[2][2];
#pragma unroll
        for (int mt = 0; mt < 4; mt++) {
            fa[mt][0] = *(const bf16x8*)&Lb[raw + (mt << 10) + ph0];
            fa[mt][1] = *(const bf16x8*)&Lb[raw + (mt << 10) + ph1];
        }
#pragma unroll
        for (int ntt = 0; ntt < 2; ntt++) {
            fb[ntt][0] = *(const bf16x8*)&Lb[rbw + (ntt << 10) + ph0];
            fb[ntt][1] = *(const bf16x8*)&Lb[rbw + (ntt << 10) + ph1];
        }
        STAGE(t + 2, bs);
        BAR;
        __builtin_amdgcn_s_setprio(1);
#pragma unroll
        for (int mt = 0; mt < 4; mt++)
#pragma unroll
            for (int ntt = 0; ntt < 2; ntt++)
                acc[mt][ntt] = __builtin_amdgcn_mfma_f32_32x32x16_bf16(
                    fa[mt][0], fb[ntt][0], acc[mt][ntt], 0, 0, 0);
#pragma unroll
        for (int mt = 0; mt < 4; mt++)
#pragma unroll
            for (int ntt = 0; ntt < 2; ntt++)
                acc[mt][ntt] = __builtin_amdgcn_mfma_f32_32x32x16_bf16(
                    fa[mt][1], fb[ntt][1], acc[mt][ntt], 0, 0, 0);
        __builtin_amdgcn_s_setprio(0);
        if (t + 2 < nt) { VM4; } else { VM0; }   // publish tile t+1
        BAR; SB0;
        b = (b == 2) ? 0 : b + 1;
        bs = (bs == 2) ? 0 : bs + 1;
    }
#undef STAGE

    // ---- epilogue: C/D layout col=lane&31, row=(reg&3)+8*(reg>>2)+4*(lane>>5) ----
    const int colb = n0 + (wc << 6) + (lane & 31);     // col for ntt=0
    const int rql = ((lane >> 5) << 2);                // +4 for upper half-wave
    if (mode == 2) {
        float* C = (float*)Cout;
#pragma unroll
        for (int mt = 0; mt < 4; mt++)
#pragma unroll
            for (int g = 0; g < 4; g++)
#pragma unroll
                for (int q = 0; q < 4; q++) {
                    int m = m0 + (wr << 7) + (mt << 5) + (g << 3) + rql + q;
                    int reg = (g << 2) + q;
                    float* row = C + (size_t)m * N + colb;
                    row[0]  = acc[mt][0][reg];
                    row[32] = acc[mt][1][reg];
                }
    } else if (n0 < 2048) {                   // fused QKV: RoPE region (Q and K)
        u16* C = (u16*)Cout;
#pragma unroll
        for (int mt = 0; mt < 4; mt++)
#pragma unroll
            for (int g = 0; g < 4; g++)
#pragma unroll
                for (int q = 0; q < 4; q++) {
                    int m = m0 + (wr << 7) + (mt << 5) + (g << 3) + rql + q;
                    int reg = (g << 2) + q;
                    const float* cb = cosp + ((size_t)m << 6);
                    const float* sb = sinp + ((size_t)m << 6);
                    u16* row = C + (size_t)m * N + colb;
                    int d0 = lane & 31;                    // ntt=0: d in [0,32)
                    float v0 = acc[mt][0][reg], v1 = acc[mt][1][reg];
                    float o0 = fmaf(v0, cb[d0],      -v1 * sb[d0]);
                    float o1 = fmaf(v1, cb[d0 + 32],  v0 * sb[d0 + 32]);
                    row[0]  = bf16u(o0);
                    row[32] = bf16u(o1);
                }
    } else {                                  // V region: plain bf16
        u16* C = (u16*)Cout;
#pragma unroll
        for (int mt = 0; mt < 4; mt++)
#pragma unroll
            for (int g = 0; g < 4; g++)
#pragma unroll
                for (int q = 0; q < 4; q++) {
                    int m = m0 + (wr << 7) + (mt << 5) + (g << 3) + rql + q;
                    int reg = (g << 2) + q;
                    u16* row = C + (size_t)m * N + colb;
                    row[0]  = bf16u(acc[mt][0][reg]);
                    row[32] = bf16u(acc[mt][1][reg]);
                }
    }
}

// ------- axial attention, both passes in one launch (4096 blocks) ----------
// qkv: (16384 x 3072) bf16 [q|k|v]. blocks [0,2048) = width, [2048,4096) = height.
__global__ __launch_bounds__(256) void axial_attn(
    const u16* __restrict__ qkv, const float* __restrict__ mask,
    u16* __restrict__ cat)
{
    __shared__ u16 Kl[128 * 64];    // XOR-swizzled 16B chunks (^ row&7)
    __shared__ u16 VT[64 * 128];    // V^T, swizzled (^ d&15)
    __shared__ u16 Pl[128 * 128];   // P (q-major), swizzled (^ q&15)
    const int hmode = blockIdx.x >> 11;
    const int o2 = blockIdx.x & 2047;
    const int b = (o2 & 7) * 256 + (o2 >> 3);   // per-half XCD chunk swizzle
    const int a = b >> 4, hd = b & 15;
    const int tid = threadIdx.x, wid = tid >> 6, lane = tid & 63;
    const int tmul = hmode ? 128 : 1;
    const int tadd = hmode ? a : (a << 7);
    const size_t hoff = (size_t)hd << 6;

#pragma unroll
    for (int c = 0; c < 4; c++) {
        int row = (wid << 5) + (c << 3) + (lane >> 3);
        int sc = (lane & 7) ^ (row & 7);
        gl_lds16(qkv + (size_t)(row * tmul + tadd) * 3072 + 1024 + hoff + (sc << 3),
                 &Kl[((wid << 5) + (c << 3)) << 6]);
    }
#pragma unroll
    for (int i = 0; i < 4; i++) {
        int cid = tid + (i << 8);
        int j = cid >> 3;
        int d0 = (cid & 7) << 3;
        uint4 raw = *(const uint4*)(qkv + (size_t)(j * tmul + tadd) * 3072 + 2048 + hoff + d0);
        const u16* e = (const u16*)&raw;
#pragma unroll
        for (int t = 0; t < 8; t++) {
            int d = d0 + t;
            VT[(d << 7) + (((j >> 3) ^ (d & 15)) << 3) + (j & 7)] = e[t];
        }
    }
    bf16x8 aq[2][2];
#pragma unroll
    for (int qt = 0; qt < 2; qt++)
#pragma unroll
        for (int ks = 0; ks < 2; ks++) {
            int row = (wid << 5) + (qt << 4) + (lane & 15);
            aq[qt][ks] = *(const bf16x8*)(qkv + (size_t)(row * tmul + tadd) * 3072 + hoff
                                          + (ks << 5) + ((lane >> 4) << 3));
        }
    __syncthreads();

    typedef float f32x4 __attribute__((ext_vector_type(4)));
    f32x4 S[2][8] = {};
#pragma unroll
    for (int kt = 0; kt < 8; kt++) {
        bf16x8 bk[2];
#pragma unroll
        for (int ks = 0; ks < 2; ks++) {
            int row = (kt << 4) + (lane & 15);
            int ch = ((ks << 2) + (lane >> 4)) ^ (row & 7);
            bk[ks] = *(const bf16x8*)&Kl[(row << 6) + (ch << 3)];
        }
#pragma unroll
        for (int qt = 0; qt < 2; qt++) {
            S[qt][kt] = __builtin_amdgcn_mfma_f32_16x16x32_bf16(aq[qt][0], bk[0], S[qt][kt], 0, 0, 0);
            S[qt][kt] = __builtin_amdgcn_mfma_f32_16x16x32_bf16(aq[qt][1], bk[1], S[qt][kt], 0, 0, 0);
        }
    }

    const float scale = 0.03125f;   // 1/sqrt(1024)
#pragma unroll
    for (int qt = 0; qt < 2; qt++) {
#pragma unroll
        for (int r = 0; r < 4; r++) {
            int qrow = (wid << 5) + (qt << 4) + ((lane >> 4) << 2) + r;
            const float* mrow = mask + (hmode ? (a << 7) : (qrow << 7));
            float mx = -1e30f;
#pragma unroll
            for (int kt = 0; kt < 8; kt++) {
                float sv = fmaf(S[qt][kt][r], scale, mrow[(kt << 4) + (lane & 15)]);
                S[qt][kt][r] = sv;
                mx = fmaxf(mx, sv);
            }
            mx = fmaxf(mx, __shfl_xor(mx, 1));
            mx = fmaxf(mx, __shfl_xor(mx, 2));
            mx = fmaxf(mx, __shfl_xor(mx, 4));
            mx = fmaxf(mx, __shfl_xor(mx, 8));
            float sum = 0.f;
#pragma unroll
            for (int kt = 0; kt < 8; kt++) {
                float p = __expf(S[qt][kt][r] - mx);
                S[qt][kt][r] = p;
                sum += p;
            }
            sum += __shfl_xor(sum, 1);
            sum += __shfl_xor(sum, 2);
            sum += __shfl_xor(sum, 4);
            sum += __shfl_xor(sum, 8);
            float rinv = 1.0f / sum;
#pragma unroll
            for (int kt = 0; kt < 8; kt++) {
                int kcol = (kt << 4) + (lane & 15);
                int ch = (kcol >> 3) ^ (qrow & 15);
                Pl[(qrow << 7) + (ch << 3) + (kcol & 7)] = bf16u(S[qt][kt][r] * rinv);
            }
        }
    }
    __syncthreads();

    f32x4 O[4][2] = {};
#pragma unroll
    for (int ks = 0; ks < 4; ks++) {
        bf16x8 av[4], bp[2];
#pragma unroll
        for (int dt = 0; dt < 4; dt++) {
            int drow = (dt << 4) + (lane & 15);
            int ch = ((ks << 2) + (lane >> 4)) ^ (drow & 15);
            av[dt] = *(const bf16x8*)&VT[(drow << 7) + (ch << 3)];
        }
#pragma unroll
        for (int qt = 0; qt < 2; qt++) {
            int qrow = (wid << 5) + (qt << 4) + (lane & 15);
            int ch = ((ks << 2) + (lane >> 4)) ^ (qrow & 15);
            bp[qt] = *(const bf16x8*)&Pl[(qrow << 7) + (ch << 3)];
        }
#pragma unroll
        for (int dt = 0; dt < 4; dt++)
#pragma unroll
            for (int qt = 0; qt < 2; qt++)
                O[dt][qt] = __builtin_amdgcn_mfma_f32_16x16x32_bf16(av[dt], bp[qt], O[dt][qt], 0, 0, 0);
    }

    const int cbase = (hmode ? 1024 : 0) + (hd << 6);
#pragma unroll
    for (int dt = 0; dt < 4; dt++)
#pragma unroll
        for (int qt = 0; qt < 2; qt++) {
            int qrow = (wid << 5) + (qt << 4) + (lane & 15);
            int d0 = (dt << 4) + ((lane >> 4) << 2);
            size_t base = ((size_t)(qrow * tmul + tadd) << 11) + cbase + d0;
            ushort4 pk;
            pk.x = bf16u(O[dt][qt][0]);
            pk.y = bf16u(O[dt][qt][1]);
            pk.z = bf16u(O[dt][qt][2]);
            pk.w = bf16u(O[dt][qt][3]);
            *(ushort4*)(cat + base) = pk;
        }
}

extern "C" void kernel_launch(void* const* d_in, const int* in_sizes, int n_in,
                              void* d_out, int out_size, void* d_ws, size_t ws_size,
                              hipStream_t stream)
{
    (void)in_sizes; (void)n_in; (void)out_size; (void)ws_size;
    const float* hidden = (const float*)d_in[0];
    const float* mask   = (const float*)d_in[1];
    const float* cosp   = (const float*)d_in[2];
    const float* sinp   = (const float*)d_in[3];
    const float* Wq     = (const float*)d_in[4];
    const float* Wk     = (const float*)d_in[5];
    const float* Wv     = (const float*)d_in[6];
    const float* Wo     = (const float*)d_in[7];

    char* ws = (char*)d_ws;
    u16* Xb    = (u16*)(ws);                  // 33,554,432 B
    u16* WqkvT = (u16*)(ws + 33554432);       //  6,291,456 B
    u16* cat   = (u16*)(ws);                  // 67,108,864 B (reuse, stream-ordered)
    u16* WoT   = (u16*)(ws + 67108864);       //  4,194,304 B
    u16* qkvb  = (u16*)(ws + 71303168);       // 100,663,296 B

    cvt_x_kernel<<<16384, 256, 0, stream>>>((const float4*)hidden, (ushort4*)Xb, 4194304);
    transp_all<<<dim3(32, 64, 4), 256, 0, stream>>>(Wq, Wk, Wv, Wo, WqkvT, WoT);

    // fused QKV projection + RoPE: [16384,1024] x [1024,3072]
    gemm8<<<dim3(12, 64), 512, 0, stream>>>(Xb, WqkvT, qkvb, cosp, sinp, 16384, 3072, 1024, 1);

    axial_attn<<<4096, 256, 0, stream>>>(qkvb, mask, cat);

    // output projection: [16384,2048] x [2048,1024] -> fp32
    gemm8<<<dim3(4, 64), 512, 0, stream>>>(cat, WoT, d_out, nullptr, nullptr, 16384, 1024, 2048, 2);
}